// Round 10
// baseline (371.160 us; speedup 1.0000x reference)
//
#include <hip/hip_runtime.h>
#include <hip/hip_bf16.h>

#define N_NODES 50000
#define N_EDGES 800000
#define MT_TILES 3125   // 50000 / 16
#define PR_TILES 1563   // ceil(3125 / 2) wave-pairs (2 m-tiles per wave, small kernels)

#define NBLK_SORT 200
#define CHUNK_SORT 4000   // NBLK_SORT * CHUNK_SORT == N_EDGES
#define NBKT 196          // ceil(50000 / 256)
#define AGG_G 12500       // node-groups per slice (4 nodes/block)

typedef __attribute__((ext_vector_type(8))) short frag_ab;   // 8 bf16 (4 VGPRs)
typedef __attribute__((ext_vector_type(4))) float frag_cd;   // 4 fp32 acc

static __device__ __forceinline__ unsigned short f2b(float f) {
    union { float f; unsigned u; } v; v.f = f;
    unsigned r = v.u + 0x7fffu + ((v.u >> 16) & 1u);  // RNE
    return (unsigned short)(r >> 16);
}
static __device__ __forceinline__ float b2f(unsigned short b) {
    union { float f; unsigned u; } v; v.u = ((unsigned)b) << 16;
    return v.f;
}
static __device__ __forceinline__ float blo(unsigned p) { return b2f((unsigned short)(p & 0xffffu)); }
static __device__ __forceinline__ float bhi(unsigned p) { return b2f((unsigned short)(p >> 16)); }

// ---------------- fused prep (cvt x, pack weights) + p1 bucket histogram ----------------
static __device__ __forceinline__ unsigned short packBK_elem(const float* __restrict__ Wa,
                                                             const float* __restrict__ Wb,
                                                             int Ka, int N, int idx) {
    int j = idx & 7;
    int lane = (idx >> 3) & 63;
    int rest = idx >> 9;
    int ntiles = N >> 4;
    int nt = rest % ntiles;
    int kt = rest / ntiles;
    int kk = kt * 32 + (lane >> 4) * 8 + j;
    int nn = nt * 16 + (lane & 15);
    float v = (kk < Ka) ? Wa[kk * N + nn] : Wb[(kk - Ka) * N + nn];
    return f2b(v);
}
static __device__ __forceinline__ unsigned short packBN_elem(const float* __restrict__ Wa,
                                                             const float* __restrict__ Wb,
                                                             int Na, int N, int idx) {
    int j = idx & 7;
    int lane = (idx >> 3) & 63;
    int rest = idx >> 9;
    int ntiles = N >> 4;
    int nt = rest % ntiles;
    int kt = rest / ntiles;
    int kk = kt * 32 + (lane >> 4) * 8 + j;
    int nn = nt * 16 + (lane & 15);
    float v = (nn < Na) ? Wa[kk * Na + nn] : Wb[kk * (N - Na) + (nn - Na)];
    return f2b(v);
}

#define PREP_S0 800000                 // cvt: ushort4 items (N_NODES*64/4)
#define PREP_S1 (PREP_S0 + 32768)      // B1p  128x256
#define PREP_S2 (PREP_S1 + 65536)      // B2p  256x256
#define PREP_S3 (PREP_S2 + 8192)       // Bl1p 128x64
#define PREP_S4 (PREP_S3 + 2048)       // Bl2p 64x32   -> total 908544 = 3549*256
#define PREP_BLKS 3549

__global__ __launch_bounds__(256) void prep_p1_kernel(const float4* __restrict__ x4,
                                                      ushort4* __restrict__ xb4,
                                                      const float* __restrict__ W1s,
                                                      const float* __restrict__ W1n,
                                                      const float* __restrict__ W2s,
                                                      const float* __restrict__ W2n,
                                                      const float* __restrict__ Wl1,
                                                      const float* __restrict__ Wl2,
                                                      unsigned short* __restrict__ B1p,
                                                      unsigned short* __restrict__ B2p,
                                                      unsigned short* __restrict__ Bl1p,
                                                      unsigned short* __restrict__ Bl2p,
                                                      const int* __restrict__ dst,
                                                      int* __restrict__ G) {
    __shared__ int h[256];
    int bid = blockIdx.x;
    int t = threadIdx.x;
    if (bid >= PREP_BLKS) {
        // p1: per-block bucket histogram (bucket = dst >> 8)
        int blk = bid - PREP_BLKS;
        h[t] = 0;
        __syncthreads();
        int base = blk * CHUNK_SORT;
        for (int i = t; i < CHUNK_SORT; i += 256)
            atomicAdd(&h[dst[base + i] >> 8], 1);
        __syncthreads();
        G[blk * 256 + t] = h[t];
        return;
    }
    int idx = bid * 256 + t;
    if (idx < PREP_S0) {
        float4 v = x4[idx];
        ushort4 o;
        o.x = f2b(v.x); o.y = f2b(v.y); o.z = f2b(v.z); o.w = f2b(v.w);
        xb4[idx] = o;
    } else if (idx < PREP_S1) {
        int i = idx - PREP_S0;
        B1p[i] = packBK_elem(W1s, W1n, 64, 256, i);
    } else if (idx < PREP_S2) {
        int i = idx - PREP_S1;
        B2p[i] = packBN_elem(W2s, W2n, 128, 256, i);
    } else if (idx < PREP_S3) {
        int i = idx - PREP_S2;
        Bl1p[i] = packBK_elem(Wl1, Wl1, 128, 64, i);
    } else {
        int i = idx - PREP_S3;
        Bl2p[i] = packBK_elem(Wl2, Wl2, 64, 32, i);
    }
}

// ---------------- CSR build: parallel scans, no global atomics ----------------

// p2a: one block per bucket column b — scan G[0..199][b] across blocks
__global__ __launch_bounds__(256) void p2a_scan(int* __restrict__ G,
                                                int* __restrict__ colsum) {
    __shared__ int sc[256];
    int b = blockIdx.x;
    int t = threadIdx.x;
    int v = (t < NBLK_SORT) ? G[t * 256 + b] : 0;
    sc[t] = v;
    __syncthreads();
    for (int off = 1; off < 256; off <<= 1) {
        int add = (t >= off) ? sc[t - off] : 0;
        __syncthreads();
        sc[t] += add;
        __syncthreads();
    }
    if (t < NBLK_SORT) G[t * 256 + b] = sc[t] - v;  // exclusive within-bucket prefix
    if (t == 255) colsum[b] = sc[255];
}

// p2b: scan bucket totals -> bucket_off (exclusive)
__global__ __launch_bounds__(256) void p2b_scan(const int* __restrict__ colsum,
                                                int* __restrict__ bucket_off,
                                                int* __restrict__ row_off) {
    __shared__ int sc[256];
    int t = threadIdx.x;
    int v = colsum[t];
    sc[t] = v;
    __syncthreads();
    for (int off = 1; off < 256; off <<= 1) {
        int add = (t >= off) ? sc[t - off] : 0;
        __syncthreads();
        sc[t] += add;
        __syncthreads();
    }
    bucket_off[t] = sc[t] - v;  // exclusive
    if (t == 255) row_off[N_NODES] = sc[255];  // == N_EDGES
}

// p3: scatter edges into bucket-grouped arrays via LDS cursors (bucket_off folded in)
__global__ __launch_bounds__(256) void p3_scatter(const int* __restrict__ src,
                                                  const int* __restrict__ dst,
                                                  const float* __restrict__ w,
                                                  const int* __restrict__ G,
                                                  const int* __restrict__ bucket_off,
                                                  int* __restrict__ bdst,
                                                  int2* __restrict__ bsedge) {
    __shared__ int cur[256];
    int t = threadIdx.x;
    cur[t] = G[blockIdx.x * 256 + t] + bucket_off[t];
    __syncthreads();
    int base = blockIdx.x * CHUNK_SORT;
    for (int i = t; i < CHUNK_SORT; i += 256) {
        int e = base + i;
        int d = dst[e];
        int pos = atomicAdd(&cur[d >> 8], 1);
        bdst[pos] = d;
        bsedge[pos] = make_int2(src[e], __float_as_int(w[e]));
    }
}

// p4: one block per bucket — LDS counting sort by dst, emit row_off/inv_deg/sedge
__global__ __launch_bounds__(256) void p4_sort(const int* __restrict__ bucket_off,
                                               const int* __restrict__ bdst,
                                               const int2* __restrict__ bsedge,
                                               int* __restrict__ row_off,
                                               float* __restrict__ inv_deg,
                                               int2* __restrict__ sedge) {
    __shared__ int lcnt[256];
    __shared__ int lcur[256];
    __shared__ int sc[256];
    int t = threadIdx.x;
    int b = blockIdx.x;
    int e0 = bucket_off[b], e1 = bucket_off[b + 1];
    int d0 = b << 8;
    lcnt[t] = 0;
    __syncthreads();
    for (int e = e0 + t; e < e1; e += 256)
        atomicAdd(&lcnt[bdst[e] - d0], 1);
    __syncthreads();
    int v = lcnt[t];
    sc[t] = v;
    __syncthreads();
    for (int off = 1; off < 256; off <<= 1) {
        int add = (t >= off) ? sc[t - off] : 0;
        __syncthreads();
        sc[t] += add;
        __syncthreads();
    }
    int loff = e0 + sc[t] - v;  // exclusive, global
    lcur[t] = loff;
    int d = d0 + t;
    if (d < N_NODES) {
        row_off[d] = loff;
        inv_deg[d] = 1.0f / (float)(v > 0 ? v : 1);
    }
    __syncthreads();
    for (int e = e0 + t; e < e1; e += 256) {
        int dd = bdst[e];
        int2 sv = bsedge[e];
        int pos = atomicAdd(&lcur[dd - d0], 1);
        sedge[pos] = sv;
    }
}

// ---------------- Aggregations: dim-sliced so gather working set fits 4MB/XCD L2 ----------------
// quarter-wave per edge, 16 lanes x 4B = 64B = exactly 1 cache line per edge.

// d=64, 2 slices of 32 dims. hn1b32[n*32 + s*16 + l15]
__global__ __launch_bounds__(256) void agg64_kernel(const unsigned* __restrict__ xb32,
                                                    const int* __restrict__ row_off,
                                                    const int2* __restrict__ sedge,
                                                    const float* __restrict__ inv_deg,
                                                    unsigned* __restrict__ hn1b32) {
    int bi = blockIdx.x;
    int s = bi / AGG_G;          // slice 0..1
    int g = bi - s * AGG_G;
    int tid = threadIdx.x;
    int lane = tid & 63;
    int qr = lane >> 4;
    int l15 = lane & 15;
    int n = g * 4 + (tid >> 6);
    int xoff = s * 16 + l15;     // uint offset within 32-uint row
    int e0 = row_off[n], e1 = row_off[n + 1];
    float a0 = 0.f, a1 = 0.f;
    int e = e0;
    for (; e + 32 <= e1; e += 32) {
        int2 m0 = sedge[e + qr];
        int2 m1 = sedge[e + 4 + qr];
        int2 m2 = sedge[e + 8 + qr];
        int2 m3 = sedge[e + 12 + qr];
        int2 m4 = sedge[e + 16 + qr];
        int2 m5 = sedge[e + 20 + qr];
        int2 m6 = sedge[e + 24 + qr];
        int2 m7 = sedge[e + 28 + qr];
        unsigned p0 = xb32[m0.x * 32 + xoff];
        unsigned p1 = xb32[m1.x * 32 + xoff];
        unsigned p2 = xb32[m2.x * 32 + xoff];
        unsigned p3 = xb32[m3.x * 32 + xoff];
        unsigned p4 = xb32[m4.x * 32 + xoff];
        unsigned p5 = xb32[m5.x * 32 + xoff];
        unsigned p6 = xb32[m6.x * 32 + xoff];
        unsigned p7 = xb32[m7.x * 32 + xoff];
        float w0 = __int_as_float(m0.y), w1 = __int_as_float(m1.y);
        float w2 = __int_as_float(m2.y), w3 = __int_as_float(m3.y);
        float w4 = __int_as_float(m4.y), w5 = __int_as_float(m5.y);
        float w6 = __int_as_float(m6.y), w7 = __int_as_float(m7.y);
        a0 += w0 * blo(p0) + w1 * blo(p1) + w2 * blo(p2) + w3 * blo(p3)
            + w4 * blo(p4) + w5 * blo(p5) + w6 * blo(p6) + w7 * blo(p7);
        a1 += w0 * bhi(p0) + w1 * bhi(p1) + w2 * bhi(p2) + w3 * bhi(p3)
            + w4 * bhi(p4) + w5 * bhi(p5) + w6 * bhi(p6) + w7 * bhi(p7);
    }
    for (; e < e1; e += 4) {
        int ee = e + qr;
        if (ee < e1) {
            int2 m = sedge[ee];
            unsigned p = xb32[m.x * 32 + xoff];
            float w = __int_as_float(m.y);
            a0 += w * blo(p);
            a1 += w * bhi(p);
        }
    }
    a0 += __shfl_xor(a0, 16, 64); a1 += __shfl_xor(a1, 16, 64);
    a0 += __shfl_xor(a0, 32, 64); a1 += __shfl_xor(a1, 32, 64);
    if (qr == 0) {
        float id = inv_deg[n];
        hn1b32[n * 32 + xoff] = (unsigned)f2b(a0 * id) | ((unsigned)f2b(a1 * id) << 16);
    }
}

// d=128, 4 slices of 32 dims. sz row = 256 bf16 (128 uints): self=uints 0..63, z=uints 64..127.
// emb fp32 out = b2f(self) + agg*inv_deg ; embb bf16 copy.
__global__ __launch_bounds__(256) void agg128_kernel(const unsigned* __restrict__ sz32,
                                                     const int* __restrict__ row_off,
                                                     const int2* __restrict__ sedge,
                                                     const float* __restrict__ inv_deg,
                                                     float* __restrict__ emb,
                                                     unsigned* __restrict__ embb32) {
    int bi = blockIdx.x;
    int s = bi / AGG_G;          // slice 0..3
    int g = bi - s * AGG_G;
    int tid = threadIdx.x;
    int lane = tid & 63;
    int qr = lane >> 4;
    int l15 = lane & 15;
    int n = g * 4 + (tid >> 6);
    int soff = s * 16 + l15;     // uint offset within self/z 64-uint halves
    int zoff = 64 + soff;
    int e0 = row_off[n], e1 = row_off[n + 1];
    float a0 = 0.f, a1 = 0.f;
    int e = e0;
    for (; e + 32 <= e1; e += 32) {
        int2 m0 = sedge[e + qr];
        int2 m1 = sedge[e + 4 + qr];
        int2 m2 = sedge[e + 8 + qr];
        int2 m3 = sedge[e + 12 + qr];
        int2 m4 = sedge[e + 16 + qr];
        int2 m5 = sedge[e + 20 + qr];
        int2 m6 = sedge[e + 24 + qr];
        int2 m7 = sedge[e + 28 + qr];
        unsigned p0 = sz32[m0.x * 128 + zoff];
        unsigned p1 = sz32[m1.x * 128 + zoff];
        unsigned p2 = sz32[m2.x * 128 + zoff];
        unsigned p3 = sz32[m3.x * 128 + zoff];
        unsigned p4 = sz32[m4.x * 128 + zoff];
        unsigned p5 = sz32[m5.x * 128 + zoff];
        unsigned p6 = sz32[m6.x * 128 + zoff];
        unsigned p7 = sz32[m7.x * 128 + zoff];
        float w0 = __int_as_float(m0.y), w1 = __int_as_float(m1.y);
        float w2 = __int_as_float(m2.y), w3 = __int_as_float(m3.y);
        float w4 = __int_as_float(m4.y), w5 = __int_as_float(m5.y);
        float w6 = __int_as_float(m6.y), w7 = __int_as_float(m7.y);
        a0 += w0 * blo(p0) + w1 * blo(p1) + w2 * blo(p2) + w3 * blo(p3)
            + w4 * blo(p4) + w5 * blo(p5) + w6 * blo(p6) + w7 * blo(p7);
        a1 += w0 * bhi(p0) + w1 * bhi(p1) + w2 * bhi(p2) + w3 * bhi(p3)
            + w4 * bhi(p4) + w5 * bhi(p5) + w6 * bhi(p6) + w7 * bhi(p7);
    }
    for (; e < e1; e += 4) {
        int ee = e + qr;
        if (ee < e1) {
            int2 m = sedge[ee];
            unsigned p = sz32[m.x * 128 + zoff];
            float w = __int_as_float(m.y);
            a0 += w * blo(p);
            a1 += w * bhi(p);
        }
    }
    a0 += __shfl_xor(a0, 16, 64); a1 += __shfl_xor(a1, 16, 64);
    a0 += __shfl_xor(a0, 32, 64); a1 += __shfl_xor(a1, 32, 64);
    if (qr == 0) {
        float id = inv_deg[n];
        unsigned sp = sz32[n * 128 + soff];
        float vx = blo(sp) + a0 * id;
        float vy = bhi(sp) + a1 * id;
        ((float2*)emb)[n * 64 + soff] = make_float2(vx, vy);
        embb32[n * 64 + soff] = (unsigned)f2b(vx) | ((unsigned)f2b(vy) << 16);
    }
}

// ---------------- MFMA GEMMs: 1 m-tile/wave, B staged per-kt through 16 KB LDS ----------------

// x1b = bf16(relu([xb|hn1b] @ [W1s;W1n] + b1))   K=128 (4 kt), N=256
__global__ __launch_bounds__(256) void gemm1_mfma(const unsigned short* __restrict__ xb,
                                                  const unsigned short* __restrict__ hn1b,
                                                  const unsigned short* __restrict__ Bp,
                                                  const float* __restrict__ b1,
                                                  unsigned short* __restrict__ x1b) {
    __shared__ __align__(16) unsigned short sB[8192];
    int tid = threadIdx.x;
    int lane = tid & 63;
    int wv = tid >> 6;
    int mt = blockIdx.x * 4 + wv;
    if (mt >= MT_TILES) mt = MT_TILES - 1;  // dup wave, benign same-value stores
    int q = lane >> 4;
    int rl = lane & 15;
    int row = mt * 16 + rl;
    frag_ab a[4];
    a[0] = *(const frag_ab*)(xb + row * 64 + q * 8);
    a[1] = *(const frag_ab*)(xb + row * 64 + q * 8 + 32);
    a[2] = *(const frag_ab*)(hn1b + row * 64 + q * 8);
    a[3] = *(const frag_ab*)(hn1b + row * 64 + q * 8 + 32);
    frag_cd acc[16];
    #pragma unroll
    for (int nt = 0; nt < 16; nt++) acc[nt] = (frag_cd){0.f, 0.f, 0.f, 0.f};
    #pragma unroll
    for (int kt = 0; kt < 4; kt++) {
        __syncthreads();
        #pragma unroll
        for (int i = 0; i < 4; i++) {
            int idx = i * 256 + tid;
            ((float4*)sB)[idx] = ((const float4*)(Bp + kt * 8192))[idx];
        }
        __syncthreads();
        #pragma unroll
        for (int nt = 0; nt < 16; nt++) {
            frag_ab b = *(const frag_ab*)(sB + (nt * 64 + lane) * 8);
            acc[nt] = __builtin_amdgcn_mfma_f32_16x16x32_bf16(a[kt], b, acc[nt], 0, 0, 0);
        }
    }
    int r0 = mt * 16;
    #pragma unroll
    for (int nt = 0; nt < 16; nt++) {
        int c = nt * 16 + rl;
        float bias = b1[c];
        #pragma unroll
        for (int i = 0; i < 4; i++) {
            int r = r0 + q * 4 + i;
            float v = acc[nt][i] + bias;
            v = v > 0.f ? v : 0.f;
            x1b[r * 256 + c] = f2b(v);
        }
    }
}

// sz = bf16[ x1b@W2s + b2 | x1b@W2n ]   K=256 (8 kt), N=256, all-bf16 output
__global__ __launch_bounds__(256) void gemm2_mfma(const unsigned short* __restrict__ x1b,
                                                  const unsigned short* __restrict__ Bp,
                                                  const float* __restrict__ b2,
                                                  unsigned short* __restrict__ sz) {
    __shared__ __align__(16) unsigned short sB[8192];
    int tid = threadIdx.x;
    int lane = tid & 63;
    int wv = tid >> 6;
    int mt = blockIdx.x * 4 + wv;
    if (mt >= MT_TILES) mt = MT_TILES - 1;
    int q = lane >> 4;
    int rl = lane & 15;
    int row = mt * 16 + rl;
    const unsigned short* arow = x1b + row * 256 + q * 8;
    frag_ab a[8];
    #pragma unroll
    for (int kt = 0; kt < 8; kt++) a[kt] = *(const frag_ab*)(arow + kt * 32);
    frag_cd acc[16];
    #pragma unroll
    for (int nt = 0; nt < 16; nt++) acc[nt] = (frag_cd){0.f, 0.f, 0.f, 0.f};
    #pragma unroll
    for (int kt = 0; kt < 8; kt++) {
        __syncthreads();
        #pragma unroll
        for (int i = 0; i < 4; i++) {
            int idx = i * 256 + tid;
            ((float4*)sB)[idx] = ((const float4*)(Bp + kt * 8192))[idx];
        }
        __syncthreads();
        #pragma unroll
        for (int nt = 0; nt < 16; nt++) {
            frag_ab b = *(const frag_ab*)(sB + (nt * 64 + lane) * 8);
            acc[nt] = __builtin_amdgcn_mfma_f32_16x16x32_bf16(a[kt], b, acc[nt], 0, 0, 0);
        }
    }
    int r0 = mt * 16;
    #pragma unroll
    for (int nt = 0; nt < 16; nt++) {
        int c = nt * 16 + rl;
        float bias = (nt < 8) ? b2[c] : 0.f;   // self half gets +b2; z half raw
        #pragma unroll
        for (int i = 0; i < 4; i++) {
            int r = r0 + q * 4 + i;
            sz[r * 256 + c] = f2b(acc[nt][i] + bias);
        }
    }
}

// h64b = bf16(relu(embb @ Wl1 + bl1))   K=128, N=64 — 2 m-tiles/wave (only 32 acc regs)
__global__ __launch_bounds__(256) void mlp1_mfma(const unsigned short* __restrict__ embb,
                                                 const unsigned short* __restrict__ Bp,
                                                 const float* __restrict__ bl1,
                                                 unsigned short* __restrict__ h64b) {
    int tid = threadIdx.x;
    int lane = tid & 63;
    int wv = tid >> 6;
    int pr = blockIdx.x * 4 + wv;
    if (pr >= PR_TILES) pr = PR_TILES - 1;
    int mt0 = pr * 2;
    int mt1 = mt0 + 1; if (mt1 >= MT_TILES) mt1 = MT_TILES - 1;
    int q = lane >> 4;
    int rl = lane & 15;
    const unsigned short* a0row = embb + (mt0 * 16 + rl) * 128 + q * 8;
    const unsigned short* a1row = embb + (mt1 * 16 + rl) * 128 + q * 8;
    const frag_ab* bp = (const frag_ab*)Bp;
    frag_cd acc0[4], acc1[4];
    #pragma unroll
    for (int nt = 0; nt < 4; nt++) {
        acc0[nt] = (frag_cd){0.f, 0.f, 0.f, 0.f};
        acc1[nt] = (frag_cd){0.f, 0.f, 0.f, 0.f};
    }
    #pragma unroll
    for (int kt = 0; kt < 4; kt++) {
        frag_ab a0 = *(const frag_ab*)(a0row + kt * 32);
        frag_ab a1 = *(const frag_ab*)(a1row + kt * 32);
        #pragma unroll
        for (int nt = 0; nt < 4; nt++) {
            frag_ab b = bp[(kt * 4 + nt) * 64 + lane];
            acc0[nt] = __builtin_amdgcn_mfma_f32_16x16x32_bf16(a0, b, acc0[nt], 0, 0, 0);
            acc1[nt] = __builtin_amdgcn_mfma_f32_16x16x32_bf16(a1, b, acc1[nt], 0, 0, 0);
        }
    }
    int r0a = mt0 * 16 + q * 4, r0b = mt1 * 16 + q * 4;
    #pragma unroll
    for (int nt = 0; nt < 4; nt++) {
        int c = nt * 16 + rl;
        float bias = bl1[c];
        #pragma unroll
        for (int i = 0; i < 4; i++) {
            float v0 = acc0[nt][i] + bias;
            float v1 = acc1[nt][i] + bias;
            h64b[(r0a + i) * 64 + c] = f2b(v0 > 0.f ? v0 : 0.f);
            h64b[(r0b + i) * 64 + c] = f2b(v1 > 0.f ? v1 : 0.f);
        }
    }
}

// fused: h32 = relu(h64b @ Wl2 + bl2) (MFMA -> LDS), out = h32 @ Wl3 + bl3
__global__ __launch_bounds__(256) void mlp23_mfma(const unsigned short* __restrict__ h64b,
                                                  const unsigned short* __restrict__ Bp,
                                                  const float* __restrict__ bl2,
                                                  const float* __restrict__ Wl3,
                                                  const float* __restrict__ bl3,
                                                  float* __restrict__ out) {
    __shared__ float hs[64][33];
    int tid = threadIdx.x;
    int lane = tid & 63;
    int wv = tid >> 6;
    int mt = blockIdx.x * 4 + wv;
    if (mt >= MT_TILES) mt = MT_TILES - 1;
    int q = lane >> 4;
    int rl = lane & 15;
    const unsigned short* arow = h64b + (mt * 16 + rl) * 64 + q * 8;
    const frag_ab* bp = (const frag_ab*)Bp;
    frag_cd acc[2];
    #pragma unroll
    for (int nt = 0; nt < 2; nt++) acc[nt] = (frag_cd){0.f, 0.f, 0.f, 0.f};
    #pragma unroll
    for (int kt = 0; kt < 2; kt++) {
        frag_ab a = *(const frag_ab*)(arow + kt * 32);
        #pragma unroll
        for (int nt = 0; nt < 2; nt++) {
            frag_ab b = bp[(kt * 2 + nt) * 64 + lane];
            acc[nt] = __builtin_amdgcn_mfma_f32_16x16x32_bf16(a, b, acc[nt], 0, 0, 0);
        }
    }
    #pragma unroll
    for (int nt = 0; nt < 2; nt++) {
        int c = nt * 16 + rl;
        float bias = bl2[c];
        #pragma unroll
        for (int i = 0; i < 4; i++) {
            int lr = wv * 16 + q * 4 + i;
            float v = acc[nt][i] + bias;
            hs[lr][c] = v > 0.f ? v : 0.f;
        }
    }
    __syncthreads();
    int base = blockIdx.x * 64;
    for (int idx = tid; idx < 640; idx += 256) {
        int lr = idx / 10;
        int j = idx - lr * 10;
        int n = base + lr;
        if (n < N_NODES) {
            float a = bl3[j];
            #pragma unroll
            for (int k = 0; k < 32; k++) a += hs[lr][k] * Wl3[k * 10 + j];
            out[n * 10 + j] = a;
        }
    }
}

// ---------------- launch ----------------

extern "C" void kernel_launch(void* const* d_in, const int* in_sizes, int n_in,
                              void* d_out, int out_size, void* d_ws, size_t ws_size,
                              hipStream_t stream) {
    const float* x   = (const float*)d_in[0];
    const int* esrc  = (const int*)d_in[1];
    const int* edst  = (const int*)d_in[2];
    const float* ew  = (const float*)d_in[3];
    const float* W1s = (const float*)d_in[4];
    const float* W1n = (const float*)d_in[5];
    const float* b1  = (const float*)d_in[6];
    const float* W2s = (const float*)d_in[7];
    const float* W2n = (const float*)d_in[8];
    const float* b2  = (const float*)d_in[9];
    const float* Wl1 = (const float*)d_in[10];
    const float* bl1 = (const float*)d_in[11];
    const float* Wl2 = (const float*)d_in[12];
    const float* bl2 = (const float*)d_in[13];
    const float* Wl3 = (const float*)d_in[14];
    const float* bl3 = (const float*)d_in[15];

    float* out = (float*)d_out;       // [50000,10]
    float* emb = out + 500000;        // [50000,128] output 1

    char* ws = (char*)d_ws;
    size_t off = 0;
    auto alloc = [&](size_t bytes) -> void* {
        void* p = ws + off;
        off = (off + bytes + 255) & ~(size_t)255;
        return p;
    };
    int*   row_off = (int*)alloc((size_t)(N_NODES + 1) * 4);
    float* inv_deg = (float*)alloc((size_t)N_NODES * 4);
    int*   G       = (int*)alloc((size_t)NBLK_SORT * 256 * 4);
    int*   colsum  = (int*)alloc(256 * 4);
    int*   bkt_off = (int*)alloc(257 * 4);
    int*   bdst    = (int*)alloc((size_t)N_EDGES * 4);
    int2*  bsedge  = (int2*)alloc((size_t)N_EDGES * 8);
    int2*  sedge   = (int2*)alloc((size_t)N_EDGES * 8);
    unsigned short* xb   = (unsigned short*)alloc((size_t)N_NODES * 64 * 2);
    unsigned short* hn1b = (unsigned short*)alloc((size_t)N_NODES * 64 * 2);
    unsigned short* x1b  = (unsigned short*)alloc((size_t)N_NODES * 256 * 2);
    unsigned short* sz   = (unsigned short*)alloc((size_t)N_NODES * 256 * 2);
    unsigned short* embb = (unsigned short*)alloc((size_t)N_NODES * 128 * 2);
    unsigned short* h64b = (unsigned short*)alloc((size_t)N_NODES * 64 * 2);
    unsigned short* B1p  = (unsigned short*)alloc(128 * 256 * 2);
    unsigned short* B2p  = (unsigned short*)alloc(256 * 256 * 2);
    unsigned short* Bl1p = (unsigned short*)alloc(128 * 64 * 2);
    unsigned short* Bl2p = (unsigned short*)alloc(64 * 32 * 2);

    // fused cvt + weight packing + p1 histogram
    prep_p1_kernel<<<PREP_BLKS + NBLK_SORT, 256, 0, stream>>>(
        (const float4*)x, (ushort4*)xb, W1s, W1n, W2s, W2n, Wl1, Wl2,
        B1p, B2p, Bl1p, Bl2p, edst, G);

    // parallel scans + scatter + per-bucket sort
    p2a_scan<<<256, 256, 0, stream>>>(G, colsum);
    p2b_scan<<<1, 256, 0, stream>>>(colsum, bkt_off, row_off);
    p3_scatter<<<NBLK_SORT, 256, 0, stream>>>(esrc, edst, ew, G, bkt_off, bdst, bsedge);
    p4_sort<<<NBKT, 256, 0, stream>>>(bkt_off, bdst, bsedge, row_off, inv_deg, sedge);

    const int PBLK = (PR_TILES + 3) / 4;   // 391 (2 m-tiles per wave, small kernels)
    const int GBLK = (MT_TILES + 3) / 4;   // 782

    // layer 1: slice-major agg (2 slices) then GEMM
    agg64_kernel<<<2 * AGG_G, 256, 0, stream>>>((const unsigned*)xb, row_off, sedge,
                                                inv_deg, (unsigned*)hn1b);
    gemm1_mfma<<<GBLK, 256, 0, stream>>>(xb, hn1b, B1p, b1, x1b);

    // layer 2: GEMM first (self|z in bf16), then slice-major agg (4 slices)
    gemm2_mfma<<<GBLK, 256, 0, stream>>>(x1b, B2p, b2, sz);
    agg128_kernel<<<4 * AGG_G, 256, 0, stream>>>((const unsigned*)sz, row_off, sedge,
                                                 inv_deg, emb, (unsigned*)embb);

    // MLP head
    mlp1_mfma<<<PBLK, 256, 0, stream>>>(embb, Bl1p, bl1, h64b);
    mlp23_mfma<<<GBLK, 256, 0, stream>>>(h64b, Bl2p, bl2, Wl3, bl3, out);
}